// Round 2
// baseline (923.418 us; speedup 1.0000x reference)
//
#include <hip/hip_runtime.h>

#define S 2048
#define DM 1024
#define H 16
#define DH 64
#define LPAD 132   // 128 + 4 floats: k-major LDS row pad

// ------------- 128x128 NT GEMM body: C[m][n] = sum_k A[m][k]*B[n][k] --------
// 256 threads, 8x8 per thread as 2x2 blocks of 4x4. K-step 32, k-major LDS
// so all fragment reads are b128. head_major: C[((n>>6)*M + m)*64 + (n&63)].
__device__ __forceinline__
void gemm128_body(const float* __restrict__ A, const float* __restrict__ B,
                  float* __restrict__ C, int M, int N, int K, bool head_major)
{
  __shared__ float As[32][LPAD];   // [k][m]
  __shared__ float Bs[32][LPAD];   // [k][n]
  const int tid = threadIdx.x;
  const int tx = tid & 15, ty = tid >> 4;
  const int m0 = blockIdx.y * 128, n0 = blockIdx.x * 128;

  float acc[8][8] = {};   // [bi*4+i][bj*4+j]

  for (int k0 = 0; k0 < K; k0 += 32) {
    float4 av[4], bv[4];
#pragma unroll
    for (int p = 0; p < 4; p++) {
      const int idx = p * 256 + tid;
      const int row = idx >> 3;          // 0..127
      const int c4  = (idx & 7) * 4;     // 0,4,..,28
      av[p] = *(const float4*)&A[(size_t)(m0 + row) * K + k0 + c4];
      bv[p] = *(const float4*)&B[(size_t)(n0 + row) * K + k0 + c4];
    }
    __syncthreads();                     // prev iter done reading LDS
#pragma unroll
    for (int p = 0; p < 4; p++) {
      const int idx = p * 256 + tid;
      const int row = idx >> 3;
      const int c4  = (idx & 7) * 4;
      As[c4 + 0][row] = av[p].x; As[c4 + 1][row] = av[p].y;
      As[c4 + 2][row] = av[p].z; As[c4 + 3][row] = av[p].w;
      Bs[c4 + 0][row] = bv[p].x; Bs[c4 + 1][row] = bv[p].y;
      Bs[c4 + 2][row] = bv[p].z; Bs[c4 + 3][row] = bv[p].w;
    }
    __syncthreads();
#pragma unroll
    for (int kk = 0; kk < 32; kk++) {
      const float4 a0 = *(const float4*)&As[kk][ty * 4];
      const float4 a1 = *(const float4*)&As[kk][64 + ty * 4];
      const float4 b0 = *(const float4*)&Bs[kk][tx * 4];
      const float4 b1 = *(const float4*)&Bs[kk][64 + tx * 4];
      const float a[8] = {a0.x, a0.y, a0.z, a0.w, a1.x, a1.y, a1.z, a1.w};
      const float b[8] = {b0.x, b0.y, b0.z, b0.w, b1.x, b1.y, b1.z, b1.w};
#pragma unroll
      for (int i = 0; i < 8; i++)
#pragma unroll
        for (int j = 0; j < 8; j++)
          acc[i][j] += a[i] * b[j];
    }
  }

#pragma unroll
  for (int bi = 0; bi < 2; bi++)
#pragma unroll
    for (int i = 0; i < 4; i++) {
      const int m = m0 + bi * 64 + ty * 4 + i;
#pragma unroll
      for (int bj = 0; bj < 2; bj++) {
        const int n = n0 + bj * 64 + tx * 4;
        const float4 o = make_float4(acc[bi * 4 + i][bj * 4 + 0],
                                     acc[bi * 4 + i][bj * 4 + 1],
                                     acc[bi * 4 + i][bj * 4 + 2],
                                     acc[bi * 4 + i][bj * 4 + 3]);
        if (head_major)
          *(float4*)&C[(size_t)((n >> 6) * M + m) * 64 + (n & 63)] = o;
        else
          *(float4*)&C[(size_t)m * N + n] = o;
      }
    }
}

// one dispatch for all three projections: blockIdx.z selects (x, W, dst)
__global__ __launch_bounds__(256)
void qkv_proj(const float* __restrict__ q, const float* __restrict__ k,
              const float* __restrict__ v, const float* __restrict__ Wq,
              const float* __restrict__ Wk, const float* __restrict__ Wv,
              float* __restrict__ qhm, float* __restrict__ khm,
              float* __restrict__ vhm)
{
  const float* A; const float* Bm; float* C;
  if (blockIdx.z == 0)      { A = q; Bm = Wq; C = qhm; }
  else if (blockIdx.z == 1) { A = k; Bm = Wk; C = khm; }
  else                      { A = v; Bm = Wv; C = vhm; }
  gemm128_body(A, Bm, C, S, DM, DM, true);
}

__global__ __launch_bounds__(256)
void out_proj(const float* __restrict__ A, const float* __restrict__ B,
              float* __restrict__ C)
{
  gemm128_body(A, B, C, S, DM, DM, false);
}

// ------------- fused scores (masked, written to d_out) + PV GEMM -------------
// block: (head h, 64 query rows). Loop over 32 t-tiles of 64.
// ks buffer is reused as the score tile after QK^T (union saves LDS).
__global__ __launch_bounds__(256)
void attn_scores_pv(const float* __restrict__ qhm, const float* __restrict__ khm,
                    const float* __restrict__ vhm, const int* __restrict__ mask,
                    float* __restrict__ attn, float* __restrict__ concat)
{
  __shared__ float qs[64][68];   // pad 68 floats = 272B
  __shared__ float ks[64][68];   // K tile, then reused as masked score tile
  __shared__ float vs[64][64];
  const int tid = threadIdx.x;
  const int tx = tid & 15, ty = tid >> 4;
  const int h = blockIdx.y;
  const int s0 = blockIdx.x * 64;

  const float* qbase = qhm + ((size_t)h * S + s0) * DH;
  const float* kbase = khm + (size_t)h * S * DH;
  const float* vbase = vhm + (size_t)h * S * DH;

  // load Q tile once, pre-scaled by 1/sqrt(64)
#pragma unroll
  for (int p = 0; p < 4; p++) {
    const int idx = p * 256 + tid;
    const int row = idx >> 4, c = (idx & 15) * 4;
    float4 v = *(const float4*)&qbase[(size_t)row * DH + c];
    qs[row][c + 0] = v.x * 0.125f; qs[row][c + 1] = v.y * 0.125f;
    qs[row][c + 2] = v.z * 0.125f; qs[row][c + 3] = v.w * 0.125f;
  }

  float4 acco[4] = {};   // PV accum: rows ty*4+i, cols tx*4..tx*4+3

  for (int t0 = 0; t0 < S; t0 += 64) {
    // stage K and V tiles
#pragma unroll
    for (int p = 0; p < 4; p++) {
      const int idx = p * 256 + tid;
      const int row = idx >> 4, c = (idx & 15) * 4;
      float4 kv = *(const float4*)&kbase[(size_t)(t0 + row) * DH + c];
      float4 vv = *(const float4*)&vbase[(size_t)(t0 + row) * DH + c];
      ks[row][c + 0] = kv.x; ks[row][c + 1] = kv.y;
      ks[row][c + 2] = kv.z; ks[row][c + 3] = kv.w;
      *(float4*)&vs[row][c] = vv;
    }
    __syncthreads();

    // QK^T: srow = ty*4+i, scol = tx+16*j
    float accs[4][4] = {};
#pragma unroll
    for (int e = 0; e < 64; e += 4) {
      float4 a[4], b[4];
#pragma unroll
      for (int i = 0; i < 4; i++) a[i] = *(const float4*)&qs[ty * 4 + i][e];
#pragma unroll
      for (int j = 0; j < 4; j++) b[j] = *(const float4*)&ks[tx + 16 * j][e];
#pragma unroll
      for (int i = 0; i < 4; i++)
#pragma unroll
        for (int j = 0; j < 4; j++)
          accs[i][j] += a[i].x * b[j].x + a[i].y * b[j].y +
                        a[i].z * b[j].z + a[i].w * b[j].w;
    }
    __syncthreads();   // all reads of ks done -> safe to overwrite with scores

    // dump score fragments into ks (now the score tile)
#pragma unroll
    for (int i = 0; i < 4; i++)
#pragma unroll
      for (int j = 0; j < 4; j++)
        ks[ty * 4 + i][tx + 16 * j] = accs[i][j];
    __syncthreads();

    // coalesced pass: apply mask, write masked scores to d_out attn region
    const int* mrow = mask + (size_t)s0 * S + t0;
    float* arow = attn + ((size_t)h * S + s0) * S + t0;
#pragma unroll
    for (int p = 0; p < 16; p++) {
      const int idx = p * 256 + tid;
      const int row = idx >> 6, col = idx & 63;
      float sv = ks[row][col];
      const int mv = mrow[(size_t)row * S + col];
      sv = mv ? -1e-7f : sv;          // faithful reference quirk
      ks[row][col] = sv;
      arow[(size_t)row * S + col] = sv;
    }
    __syncthreads();

    // PV accumulate with MASKED pre-softmax scores (reference quirk)
#pragma unroll 8
    for (int tt = 0; tt < 64; tt++) {
      const float4 v4 = *(const float4*)&vs[tt][tx * 4];
#pragma unroll
      for (int i = 0; i < 4; i++) {
        const float sv = ks[ty * 4 + i][tt];
        acco[i].x += sv * v4.x;
        acco[i].y += sv * v4.y;
        acco[i].z += sv * v4.z;
        acco[i].w += sv * v4.w;
      }
    }
    __syncthreads();   // before next iteration overwrites ks/vs
  }

  // write concat[s][h*64 + dd]
  float* cbase = concat + (size_t)s0 * DM + h * DH + tx * 4;
#pragma unroll
  for (int i = 0; i < 4; i++)
    *(float4*)&cbase[(size_t)(ty * 4 + i) * DM] = acco[i];
}

// ----------------------- row softmax in-place on attn -----------------------
__global__ __launch_bounds__(256)
void softmax_rows(float* __restrict__ attn)
{
  float* row = attn + (size_t)blockIdx.x * S;
  const int tid = threadIdx.x;
  float4 a = ((const float4*)row)[tid];
  float4 b = ((const float4*)row)[tid + 256];

  float m = fmaxf(fmaxf(fmaxf(a.x, a.y), fmaxf(a.z, a.w)),
                  fmaxf(fmaxf(b.x, b.y), fmaxf(b.z, b.w)));
#pragma unroll
  for (int off = 32; off >= 1; off >>= 1)
    m = fmaxf(m, __shfl_xor(m, off));
  __shared__ float redm[4], reds[4];
  if ((tid & 63) == 0) redm[tid >> 6] = m;
  __syncthreads();
  m = fmaxf(fmaxf(redm[0], redm[1]), fmaxf(redm[2], redm[3]));

  a.x = __expf(a.x - m); a.y = __expf(a.y - m);
  a.z = __expf(a.z - m); a.w = __expf(a.w - m);
  b.x = __expf(b.x - m); b.y = __expf(b.y - m);
  b.z = __expf(b.z - m); b.w = __expf(b.w - m);
  float s = a.x + a.y + a.z + a.w + b.x + b.y + b.z + b.w;
#pragma unroll
  for (int off = 32; off >= 1; off >>= 1)
    s += __shfl_xor(s, off);
  if ((tid & 63) == 0) reds[tid >> 6] = s;
  __syncthreads();
  s = reds[0] + reds[1] + reds[2] + reds[3];

  const float inv = 1.0f / s;
  a.x *= inv; a.y *= inv; a.z *= inv; a.w *= inv;
  b.x *= inv; b.y *= inv; b.z *= inv; b.w *= inv;
  ((float4*)row)[tid] = a;
  ((float4*)row)[tid + 256] = b;
}

// ---------------------------------------------------------------------------
extern "C" void kernel_launch(void* const* d_in, const int* in_sizes, int n_in,
                              void* d_out, int out_size, void* d_ws, size_t ws_size,
                              hipStream_t stream)
{
  const float* query = (const float*)d_in[0];
  const float* key   = (const float*)d_in[1];
  const float* value = (const float*)d_in[2];
  const int*   mask  = (const int*)d_in[3];
  const float* Wq    = (const float*)d_in[4];
  const float* Wk    = (const float*)d_in[5];
  const float* Wv    = (const float*)d_in[6];
  const float* Wo    = (const float*)d_in[7];

  float* out  = (float*)d_out;                 // [S][DM]
  float* attn = out + (size_t)S * DM;          // [H][S][S]

  float* ws     = (float*)d_ws;                // 32 MB used
  float* qhm    = ws;                          // [H][S][64]
  float* khm    = qhm + (size_t)H * S * DH;
  float* vhm    = khm + (size_t)H * S * DH;
  float* concat = vhm + (size_t)H * S * DH;    // [S][DM]

  const dim3 blk(256);

  hipLaunchKernelGGL(qkv_proj, dim3(DM / 128, S / 128, 3), blk, 0, stream,
                     query, key, value, Wq, Wk, Wv, qhm, khm, vhm);

  hipLaunchKernelGGL(attn_scores_pv, dim3(S / 64, H), blk, 0, stream,
                     qhm, khm, vhm, mask, attn, concat);

  hipLaunchKernelGGL(softmax_rows, dim3(H * S), blk, 0, stream, attn);

  hipLaunchKernelGGL(out_proj, dim3(DM / 128, S / 128), blk, 0, stream,
                     concat, Wo, out);
}

// Round 3
// 737.869 us; speedup vs baseline: 1.2515x; 1.2515x over previous
//
#include <hip/hip_runtime.h>

#define S 2048
#define DM 1024
#define H 16
#define DH 64

typedef __attribute__((ext_vector_type(8))) short bf16x8;
typedef __attribute__((ext_vector_type(4))) float f32x4;

// ---- fp32 -> bf16 (RNE) and 2-term split: x ~= hi + lo (rel err ~2^-16) ----
__device__ __forceinline__ unsigned short f2bf(float x) {
  unsigned int u = __float_as_uint(x);
  u += 0x7FFFu + ((u >> 16) & 1u);
  return (unsigned short)(u >> 16);
}
__device__ __forceinline__ float bf2f(unsigned short h) {
  return __uint_as_float(((unsigned int)h) << 16);
}
__device__ __forceinline__ void split2(float x, unsigned short& h, unsigned short& l) {
  h = f2bf(x);
  l = f2bf(x - bf2f(h));
}

// c += A*B with split operands: (ah+al)*(bh+bl) ~= ah*bh + ah*bl + al*bh
__device__ __forceinline__ f32x4 mfma3(bf16x8 ah, bf16x8 al, bf16x8 bh, bf16x8 bl, f32x4 c) {
  c = __builtin_amdgcn_mfma_f32_16x16x32_bf16(ah, bh, c, 0, 0, 0);
  c = __builtin_amdgcn_mfma_f32_16x16x32_bf16(ah, bl, c, 0, 0, 0);
  c = __builtin_amdgcn_mfma_f32_16x16x32_bf16(al, bh, c, 0, 0, 0);
  return c;
}

// ---------------- MFMA NT GEMM: C[m][n] = sum_k A[m][k]*B[n][k] -------------
// 128x128 tile, 4 waves (2x2 of 64x64), 16x16x32 frags, K-step 32.
// D layout (m89-verified): n = lane&15 (+16*fj), m = (lane>>4)*4 + reg (+16*fi).
template<bool HEAD_MAJOR>
__device__ __forceinline__
void proj_body(const float* __restrict__ A, const float* __restrict__ B,
               float* __restrict__ C)
{
  __shared__ unsigned short Ah[128][40], Al[128][40];  // 40 = 32 + 8 pad (80B row, 16B-aligned)
  __shared__ unsigned short Bh[128][40], Bl[128][40];
  const int tid = threadIdx.x;
  const int lane = tid & 63, w = tid >> 6;
  const int wr = w >> 1, wc = w & 1;
  const int lg = lane >> 4, lt = lane & 15;
  const int m0 = blockIdx.y * 128, n0 = blockIdx.x * 128;

  f32x4 acc[4][4] = {};   // [fi][fj]

  for (int k0 = 0; k0 < DM; k0 += 32) {
    float4 av[4], bv[4];
#pragma unroll
    for (int p = 0; p < 4; p++) {
      const int idx = p * 256 + tid;
      const int row = idx >> 3, c4 = (idx & 7) * 4;
      av[p] = *(const float4*)&A[(size_t)(m0 + row) * DM + k0 + c4];
      bv[p] = *(const float4*)&B[(size_t)(n0 + row) * DM + k0 + c4];
    }
    __syncthreads();                      // prev iter done reading LDS
#pragma unroll
    for (int p = 0; p < 4; p++) {
      const int idx = p * 256 + tid;
      const int row = idx >> 3, c4 = (idx & 7) * 4;
      unsigned short hh, ll;
      split2(av[p].x, hh, ll); Ah[row][c4 + 0] = hh; Al[row][c4 + 0] = ll;
      split2(av[p].y, hh, ll); Ah[row][c4 + 1] = hh; Al[row][c4 + 1] = ll;
      split2(av[p].z, hh, ll); Ah[row][c4 + 2] = hh; Al[row][c4 + 2] = ll;
      split2(av[p].w, hh, ll); Ah[row][c4 + 3] = hh; Al[row][c4 + 3] = ll;
      split2(bv[p].x, hh, ll); Bh[row][c4 + 0] = hh; Bl[row][c4 + 0] = ll;
      split2(bv[p].y, hh, ll); Bh[row][c4 + 1] = hh; Bl[row][c4 + 1] = ll;
      split2(bv[p].z, hh, ll); Bh[row][c4 + 2] = hh; Bl[row][c4 + 2] = ll;
      split2(bv[p].w, hh, ll); Bh[row][c4 + 3] = hh; Bl[row][c4 + 3] = ll;
    }
    __syncthreads();

    bf16x8 bhf[4], blf[4];
#pragma unroll
    for (int fj = 0; fj < 4; fj++) {
      const int r = wc * 64 + fj * 16 + lt;
      bhf[fj] = *(const bf16x8*)&Bh[r][lg * 8];
      blf[fj] = *(const bf16x8*)&Bl[r][lg * 8];
    }
#pragma unroll
    for (int fi = 0; fi < 4; fi++) {
      const int r = wr * 64 + fi * 16 + lt;
      const bf16x8 ahf = *(const bf16x8*)&Ah[r][lg * 8];
      const bf16x8 alf = *(const bf16x8*)&Al[r][lg * 8];
#pragma unroll
      for (int fj = 0; fj < 4; fj++)
        acc[fi][fj] = mfma3(ahf, alf, bhf[fj], blf[fj], acc[fi][fj]);
    }
  }

#pragma unroll
  for (int fi = 0; fi < 4; fi++)
#pragma unroll
    for (int r = 0; r < 4; r++) {
      const int m = m0 + wr * 64 + fi * 16 + lg * 4 + r;
#pragma unroll
      for (int fj = 0; fj < 4; fj++) {
        const int n = n0 + wc * 64 + fj * 16 + lt;
        const float v = acc[fi][fj][r];
        if (HEAD_MAJOR) C[(size_t)((n >> 6) * S + m) * 64 + (n & 63)] = v;
        else            C[(size_t)m * DM + n] = v;
      }
    }
}

__global__ __launch_bounds__(256)
void qkv_proj(const float* __restrict__ q, const float* __restrict__ k,
              const float* __restrict__ v, const float* __restrict__ Wq,
              const float* __restrict__ Wk, const float* __restrict__ Wv,
              float* __restrict__ qhm, float* __restrict__ khm,
              float* __restrict__ vhm)
{
  const float* A; const float* Bm; float* C;
  if (blockIdx.z == 0)      { A = q; Bm = Wq; C = qhm; }
  else if (blockIdx.z == 1) { A = k; Bm = Wk; C = khm; }
  else                      { A = v; Bm = Wv; C = vhm; }
  proj_body<true>(A, Bm, C);
}

__global__ __launch_bounds__(256)
void out_proj(const float* __restrict__ A, const float* __restrict__ B,
              float* __restrict__ C)
{
  proj_body<false>(A, B, C);
}

// --------------- fused attention: scores + online stats + PV (phase 1),
// ---------------- recompute + normalized softmax write (phase 2) -----------
// block = (64 q-rows, head). 4 waves: wr = q-half, wc = t-half (QK) / d-half (PV).
__global__ __launch_bounds__(256)
void attn_fused(const float* __restrict__ qhm, const float* __restrict__ khm,
                const float* __restrict__ vhm, const int* __restrict__ mask,
                float* __restrict__ attn, float* __restrict__ concat)
{
  __shared__ float qps_f[64][72];                  // Q stage -> phase-2 out tile
  __shared__ unsigned short Kh[64][72], Kl[64][72];
  __shared__ unsigned short Vh[64][72], Vl[64][72];  // transposed: [d][t]
  __shared__ float mbuf[4][32], lbuf[4][32];
  unsigned short* Ph = (unsigned short*)&qps_f[0][0];  // alias: P tile [64][72] hi
  unsigned short* Pl = Ph + 64 * 72;                   // and lo (fits exactly)

  const int tid = threadIdx.x;
  const int lane = tid & 63, w = tid >> 6;
  const int wr = w >> 1, wc = w & 1;
  const int lg = lane >> 4, lt = lane & 15;
  const int h = blockIdx.y, s0 = blockIdx.x * 64;

  const float* qbase = qhm + ((size_t)h * S + s0) * DH;
  const float* kbase = khm + (size_t)h * S * DH;
  const float* vbase = vhm + (size_t)h * S * DH;

  // ---- stage Q (pre-scaled by 1/sqrt(64)) and pull per-wave A-fragments ----
#pragma unroll
  for (int p = 0; p < 4; p++) {
    const int idx = p * 256 + tid;
    const int row = idx >> 4, c4 = (idx & 15) * 4;
    float4 v = *(const float4*)&qbase[(size_t)row * DH + c4];
    v.x *= 0.125f; v.y *= 0.125f; v.z *= 0.125f; v.w *= 0.125f;
    *(float4*)&qps_f[row][c4] = v;
  }
  __syncthreads();
  bf16x8 aqh[2][2], aql[2][2];   // [fi][kstep]
#pragma unroll
  for (int fi = 0; fi < 2; fi++)
#pragma unroll
    for (int ks = 0; ks < 2; ks++) {
      const float* p8 = &qps_f[wr * 32 + fi * 16 + lt][ks * 32 + lg * 8];
#pragma unroll
      for (int j = 0; j < 8; j++) {
        unsigned short hh, ll; split2(p8[j], hh, ll);
        aqh[fi][ks][j] = (short)hh; aql[fi][ks][j] = (short)ll;
      }
    }
  __syncthreads();   // qps_f now reusable as P tile

  f32x4 ao[2][2] = {};            // PV acc [fi][fd]
  float mrow[2][4], lrow[2][4];   // online stats for q = wr*32+fi*16+lg*4+r
#pragma unroll
  for (int fi = 0; fi < 2; fi++)
#pragma unroll
    for (int r = 0; r < 4; r++) { mrow[fi][r] = -3.0e38f; lrow[fi][r] = 0.0f; }

  // =============================== phase 1 ================================
  for (int t0 = 0; t0 < S; t0 += 64) {
    // stage K (split) and V (split + transpose)
#pragma unroll
    for (int p = 0; p < 4; p++) {
      const int idx = p * 256 + tid;
      const int row = idx >> 4, c4 = (idx & 15) * 4;
      const float4 kv = *(const float4*)&kbase[(size_t)(t0 + row) * DH + c4];
      const float4 vv = *(const float4*)&vbase[(size_t)(t0 + row) * DH + c4];
      unsigned short hh, ll;
      split2(kv.x, hh, ll); Kh[row][c4 + 0] = hh; Kl[row][c4 + 0] = ll;
      split2(kv.y, hh, ll); Kh[row][c4 + 1] = hh; Kl[row][c4 + 1] = ll;
      split2(kv.z, hh, ll); Kh[row][c4 + 2] = hh; Kl[row][c4 + 2] = ll;
      split2(kv.w, hh, ll); Kh[row][c4 + 3] = hh; Kl[row][c4 + 3] = ll;
      split2(vv.x, hh, ll); Vh[c4 + 0][row] = hh; Vl[c4 + 0][row] = ll;
      split2(vv.y, hh, ll); Vh[c4 + 1][row] = hh; Vl[c4 + 1][row] = ll;
      split2(vv.z, hh, ll); Vh[c4 + 2][row] = hh; Vl[c4 + 2][row] = ll;
      split2(vv.w, hh, ll); Vh[c4 + 3][row] = hh; Vl[c4 + 3][row] = ll;
    }
    __syncthreads();

    // QK^T for this wave's 32x32 quadrant
    f32x4 sc[2][2] = {};   // [fi][fj]
#pragma unroll
    for (int ks = 0; ks < 2; ks++) {
      bf16x8 bh[2], bl[2];
#pragma unroll
      for (int fj = 0; fj < 2; fj++) {
        const int r = wc * 32 + fj * 16 + lt;
        bh[fj] = *(const bf16x8*)&Kh[r][ks * 32 + lg * 8];
        bl[fj] = *(const bf16x8*)&Kl[r][ks * 32 + lg * 8];
      }
#pragma unroll
      for (int fi = 0; fi < 2; fi++)
#pragma unroll
        for (int fj = 0; fj < 2; fj++)
          sc[fi][fj] = mfma3(aqh[fi][ks], aql[fi][ks], bh[fj], bl[fj], sc[fi][fj]);
    }

    // mask + P write (split bf16) + online m/l update
#pragma unroll
    for (int fi = 0; fi < 2; fi++)
#pragma unroll
      for (int r = 0; r < 4; r++) {
        const int q = wr * 32 + fi * 16 + lg * 4 + r;
        const int* mp = &mask[(size_t)(s0 + q) * S + t0 + wc * 32 + lt];
        float sv0 = sc[fi][0][r], sv1 = sc[fi][1][r];
        sv0 = mp[0]  ? -1e-7f : sv0;   // faithful reference quirk
        sv1 = mp[16] ? -1e-7f : sv1;
        unsigned short hh, ll;
        split2(sv0, hh, ll); Ph[q * 72 + wc * 32 + lt] = hh;      Pl[q * 72 + wc * 32 + lt] = ll;
        split2(sv1, hh, ll); Ph[q * 72 + wc * 32 + 16 + lt] = hh; Pl[q * 72 + wc * 32 + 16 + lt] = ll;
        float pm = fmaxf(sv0, sv1);
        pm = fmaxf(pm, __shfl_xor(pm, 1));
        pm = fmaxf(pm, __shfl_xor(pm, 2));
        pm = fmaxf(pm, __shfl_xor(pm, 4));
        pm = fmaxf(pm, __shfl_xor(pm, 8));
        const float mo = mrow[fi][r];
        const float mn = fmaxf(mo, pm);
        float e = __expf(sv0 - mn) + __expf(sv1 - mn);
        e += __shfl_xor(e, 1); e += __shfl_xor(e, 2);
        e += __shfl_xor(e, 4); e += __shfl_xor(e, 8);
        lrow[fi][r] = lrow[fi][r] * __expf(mo - mn) + e;
        mrow[fi][r] = mn;
      }
    __syncthreads();   // P complete; K reads done

    // PV accumulate: out[q][d] += P[q][t] * V[t][d] (raw masked scores)
#pragma unroll
    for (int ks = 0; ks < 2; ks++) {
      bf16x8 ph_[2], pl_[2], vh_[2], vl_[2];
#pragma unroll
      for (int fi = 0; fi < 2; fi++) {
        const int q = wr * 32 + fi * 16 + lt;
        ph_[fi] = *(const bf16x8*)&Ph[q * 72 + ks * 32 + lg * 8];
        pl_[fi] = *(const bf16x8*)&Pl[q * 72 + ks * 32 + lg * 8];
      }
#pragma unroll
      for (int fd = 0; fd < 2; fd++) {
        const int d = wc * 32 + fd * 16 + lt;
        vh_[fd] = *(const bf16x8*)&Vh[d][ks * 32 + lg * 8];
        vl_[fd] = *(const bf16x8*)&Vl[d][ks * 32 + lg * 8];
      }
#pragma unroll
      for (int fi = 0; fi < 2; fi++)
#pragma unroll
        for (int fd = 0; fd < 2; fd++)
          ao[fi][fd] = mfma3(ph_[fi], pl_[fi], vh_[fd], vl_[fd], ao[fi][fd]);
    }
    __syncthreads();   // before next tile's staging overwrites K/V/P
  }

  // ---- combine (m,l) across the two t-half waves sharing each q-row ----
  if (lt == 0) {
#pragma unroll
    for (int fi = 0; fi < 2; fi++)
#pragma unroll
      for (int r = 0; r < 4; r++) {
        mbuf[w][fi * 16 + lg * 4 + r] = mrow[fi][r];
        lbuf[w][fi * 16 + lg * 4 + r] = lrow[fi][r];
      }
  }
  __syncthreads();
  float fm[2][4], fil[2][4];
#pragma unroll
  for (int fi = 0; fi < 2; fi++)
#pragma unroll
    for (int r = 0; r < 4; r++) {
      const int rr = fi * 16 + lg * 4 + r;
      const float m0_ = mbuf[wr * 2 + 0][rr], m1_ = mbuf[wr * 2 + 1][rr];
      const float l0_ = lbuf[wr * 2 + 0][rr], l1_ = lbuf[wr * 2 + 1][rr];
      const float mm = fmaxf(m0_, m1_);
      const float ll = l0_ * __expf(m0_ - mm) + l1_ * __expf(m1_ - mm);
      fm[fi][r] = mm;
      fil[fi][r] = 1.0f / ll;
    }

  // ---- write concat[s][h*64+d] from PV accumulators ----
#pragma unroll
  for (int fi = 0; fi < 2; fi++)
#pragma unroll
    for (int r = 0; r < 4; r++) {
      const int qg = s0 + wr * 32 + fi * 16 + lg * 4 + r;
#pragma unroll
      for (int fd = 0; fd < 2; fd++) {
        const int d = h * 64 + wc * 32 + fd * 16 + lt;
        concat[(size_t)qg * DM + d] = ao[fi][fd][r];
      }
    }

  // =============== phase 2: recompute scores, write softmax ===============
  for (int t0 = 0; t0 < S; t0 += 64) {
    __syncthreads();   // prev iter's LDS reads done
#pragma unroll
    for (int p = 0; p < 4; p++) {
      const int idx = p * 256 + tid;
      const int row = idx >> 4, c4 = (idx & 15) * 4;
      const float4 kv = *(const float4*)&kbase[(size_t)(t0 + row) * DH + c4];
      unsigned short hh, ll;
      split2(kv.x, hh, ll); Kh[row][c4 + 0] = hh; Kl[row][c4 + 0] = ll;
      split2(kv.y, hh, ll); Kh[row][c4 + 1] = hh; Kl[row][c4 + 1] = ll;
      split2(kv.z, hh, ll); Kh[row][c4 + 2] = hh; Kl[row][c4 + 2] = ll;
      split2(kv.w, hh, ll); Kh[row][c4 + 3] = hh; Kl[row][c4 + 3] = ll;
    }
    __syncthreads();

    f32x4 sc[2][2] = {};
#pragma unroll
    for (int ks = 0; ks < 2; ks++) {
      bf16x8 bh[2], bl[2];
#pragma unroll
      for (int fj = 0; fj < 2; fj++) {
        const int r = wc * 32 + fj * 16 + lt;
        bh[fj] = *(const bf16x8*)&Kh[r][ks * 32 + lg * 8];
        bl[fj] = *(const bf16x8*)&Kl[r][ks * 32 + lg * 8];
      }
#pragma unroll
      for (int fi = 0; fi < 2; fi++)
#pragma unroll
        for (int fj = 0; fj < 2; fj++)
          sc[fi][fj] = mfma3(aqh[fi][ks], aql[fi][ks], bh[fj], bl[fj], sc[fi][fj]);
    }

#pragma unroll
    for (int fi = 0; fi < 2; fi++)
#pragma unroll
      for (int r = 0; r < 4; r++) {
        const int q = wr * 32 + fi * 16 + lg * 4 + r;
        const int* mp = &mask[(size_t)(s0 + q) * S + t0 + wc * 32 + lt];
        float sv0 = sc[fi][0][r], sv1 = sc[fi][1][r];
        sv0 = mp[0]  ? -1e-7f : sv0;
        sv1 = mp[16] ? -1e-7f : sv1;
        qps_f[q][wc * 32 + lt]      = __expf(sv0 - fm[fi][r]) * fil[fi][r];
        qps_f[q][wc * 32 + 16 + lt] = __expf(sv1 - fm[fi][r]) * fil[fi][r];
      }
    __syncthreads();

    float* abase = attn + ((size_t)h * S + s0) * S + t0;
#pragma unroll
    for (int p = 0; p < 4; p++) {
      const int idx = p * 256 + tid;
      const int row = idx >> 4, c4 = (idx & 15) * 4;
      *(float4*)&abase[(size_t)row * S + c4] = *(const float4*)&qps_f[row][c4];
    }
  }
}

// ---------------------------------------------------------------------------
extern "C" void kernel_launch(void* const* d_in, const int* in_sizes, int n_in,
                              void* d_out, int out_size, void* d_ws, size_t ws_size,
                              hipStream_t stream)
{
  const float* query = (const float*)d_in[0];
  const float* key   = (const float*)d_in[1];
  const float* value = (const float*)d_in[2];
  const int*   mask  = (const int*)d_in[3];
  const float* Wq    = (const float*)d_in[4];
  const float* Wk    = (const float*)d_in[5];
  const float* Wv    = (const float*)d_in[6];
  const float* Wo    = (const float*)d_in[7];

  float* out  = (float*)d_out;                 // [S][DM]
  float* attn = out + (size_t)S * DM;          // [H][S][S]

  float* ws     = (float*)d_ws;                // 32 MB used
  float* qhm    = ws;                          // [H][S][64]
  float* khm    = qhm + (size_t)H * S * DH;
  float* vhm    = khm + (size_t)H * S * DH;
  float* concat = vhm + (size_t)H * S * DH;    // [S][DM]

  const dim3 blk(256);

  hipLaunchKernelGGL(qkv_proj, dim3(DM / 128, S / 128, 3), blk, 0, stream,
                     query, key, value, Wq, Wk, Wv, qhm, khm, vhm);

  hipLaunchKernelGGL(attn_fused, dim3(S / 64, H), blk, 0, stream,
                     qhm, khm, vhm, mask, attn, concat);

  hipLaunchKernelGGL(out_proj, dim3(DM / 128, S / 128), blk, 0, stream,
                     concat, Wo, out);
}

// Round 6
// 614.979 us; speedup vs baseline: 1.5015x; 1.1998x over previous
//
#include <hip/hip_runtime.h>

#define S 2048
#define DM 1024
#define H 16
#define DH 64

typedef __attribute__((ext_vector_type(8))) short bf16x8;
typedef __attribute__((ext_vector_type(4))) float f32x4;
typedef __attribute__((ext_vector_type(4))) unsigned short u16x4;
typedef unsigned short u16;
typedef unsigned int u32;

// trunc-split: x = hi + rem; hi = upper-16(x) (exact), lo = RNE-bf16(rem).
// |x - hi - lo| <~ 2^-16 |x|
__device__ __forceinline__ void split2(float x, u16& h, u16& l) {
  const u32 u = __float_as_uint(x);
  const u32 hu = u & 0xFFFF0000u;
  h = (u16)(hu >> 16);
  const float rem = x - __uint_as_float(hu);
  u32 r = __float_as_uint(rem);
  r += 0x7FFFu + ((r >> 16) & 1u);
  l = (u16)(r >> 16);
}

// split into vector slots via plain temporaries (vector elements can't bind
// to non-const refs). Call with compile-time i inside unrolled loops.
__device__ __forceinline__ void split2v(float x, u16x4& h4, u16x4& l4, int i) {
  u16 hh, ll;
  split2(x, hh, ll);
  h4[i] = hh; l4[i] = ll;
}

// c += (ah+al)*(bh+bl) dropping al*bl
__device__ __forceinline__ f32x4 mfma3(bf16x8 ah, bf16x8 al, bf16x8 bh, bf16x8 bl, f32x4 c) {
  c = __builtin_amdgcn_mfma_f32_16x16x32_bf16(ah, bh, c, 0, 0, 0);
  c = __builtin_amdgcn_mfma_f32_16x16x32_bf16(ah, bl, c, 0, 0, 0);
  c = __builtin_amdgcn_mfma_f32_16x16x32_bf16(al, bh, c, 0, 0, 0);
  return c;
}

// ---------------- QKV projection: NT GEMM, split bf16 hi/lo output ----------
// z=0: Q = X_q·Wq^T, head-major [H][S][64], pre-scaled 0.125
// z=1: K = X_k·Wk^T, head-major
// z=2: V^T = Wv·X_v^T, row-major [DM][S]  (A=Wv rows d, B=X rows s)
__global__ __launch_bounds__(256)
void qkv_proj(const float* __restrict__ q, const float* __restrict__ k,
              const float* __restrict__ v, const float* __restrict__ Wq,
              const float* __restrict__ Wk, const float* __restrict__ Wv,
              u16* __restrict__ qh, u16* __restrict__ ql,
              u16* __restrict__ kh, u16* __restrict__ kl,
              u16* __restrict__ vTh, u16* __restrict__ vTl)
{
  __shared__ u16 Ah[128][40], Al[128][40], Bh[128][40], Bl[128][40]; // 80B rows
  const int tid = threadIdx.x;
  const int lane = tid & 63, w = tid >> 6;
  const int wr = w >> 1, wc = w & 1;
  const int lg = lane >> 4, lt = lane & 15;
  const int z = blockIdx.z;

  const float *A, *B;
  int m0, n0;
  if (z == 2) { A = Wv; B = v; m0 = blockIdx.y * 128; n0 = blockIdx.x * 128; }
  else {
    A = (z == 0) ? q : k; B = (z == 0) ? Wq : Wk;
    m0 = blockIdx.x * 128; n0 = blockIdx.y * 128;
  }

  f32x4 acc[4][4] = {};

  for (int k0 = 0; k0 < DM; k0 += 32) {
    float4 av[4], bv[4];
#pragma unroll
    for (int p = 0; p < 4; p++) {
      const int idx = p * 256 + tid;
      const int row = idx >> 3, c4 = (idx & 7) * 4;
      av[p] = *(const float4*)&A[(size_t)(m0 + row) * DM + k0 + c4];
      bv[p] = *(const float4*)&B[(size_t)(n0 + row) * DM + k0 + c4];
    }
    __syncthreads();                      // prev iter done reading LDS
#pragma unroll
    for (int p = 0; p < 4; p++) {
      const int idx = p * 256 + tid;
      const int row = idx >> 3, c4 = (idx & 7) * 4;
      u16x4 h4, l4;
      split2v(av[p].x, h4, l4, 0); split2v(av[p].y, h4, l4, 1);
      split2v(av[p].z, h4, l4, 2); split2v(av[p].w, h4, l4, 3);
      *(u16x4*)&Ah[row][c4] = h4; *(u16x4*)&Al[row][c4] = l4;
      split2v(bv[p].x, h4, l4, 0); split2v(bv[p].y, h4, l4, 1);
      split2v(bv[p].z, h4, l4, 2); split2v(bv[p].w, h4, l4, 3);
      *(u16x4*)&Bh[row][c4] = h4; *(u16x4*)&Bl[row][c4] = l4;
    }
    __syncthreads();

    bf16x8 bhf[4], blf[4];
#pragma unroll
    for (int fj = 0; fj < 4; fj++) {
      const int r = wc * 64 + fj * 16 + lt;
      bhf[fj] = *(const bf16x8*)&Bh[r][lg * 8];
      blf[fj] = *(const bf16x8*)&Bl[r][lg * 8];
    }
#pragma unroll
    for (int fi = 0; fi < 4; fi++) {
      const int r = wr * 64 + fi * 16 + lt;
      const bf16x8 ahf = *(const bf16x8*)&Ah[r][lg * 8];
      const bf16x8 alf = *(const bf16x8*)&Al[r][lg * 8];
#pragma unroll
      for (int fj = 0; fj < 4; fj++)
        acc[fi][fj] = mfma3(ahf, alf, bhf[fj], blf[fj], acc[fi][fj]);
    }
  }

  u16 *dh, *dl;
  float scale;
  if (z == 0)      { dh = qh;  dl = ql;  scale = 0.125f; }
  else if (z == 1) { dh = kh;  dl = kl;  scale = 1.0f; }
  else             { dh = vTh; dl = vTl; scale = 1.0f; }

#pragma unroll
  for (int fi = 0; fi < 4; fi++)
#pragma unroll
    for (int r = 0; r < 4; r++) {
      const int m = m0 + wr * 64 + fi * 16 + lg * 4 + r;
#pragma unroll
      for (int fj = 0; fj < 4; fj++) {
        const int n = n0 + wc * 64 + fj * 16 + lt;
        const size_t addr = (z == 2) ? ((size_t)m * S + n)
                                     : ((size_t)((n >> 6) * S + m) * 64 + (n & 63));
        u16 hh, ll;
        split2(acc[fi][fj][r] * scale, hh, ll);
        dh[addr] = hh; dl[addr] = ll;
      }
    }
}

// ---------------- fused raw-score write + PV (no softmax work here) ---------
// block = (64 q-rows, head); 4 waves, each owns 16 q-rows, full t extent.
// Scores computed TRANSPOSED (mfma(K,Q)): lane holds 4 consecutive t per reg.
__global__ __launch_bounds__(256)
void attn_pv(const u16* __restrict__ qh, const u16* __restrict__ ql,
             const u16* __restrict__ kh, const u16* __restrict__ kl,
             const u16* __restrict__ vTh, const u16* __restrict__ vTl,
             const int* __restrict__ mask,
             float* __restrict__ attn, u16* __restrict__ ch, u16* __restrict__ cl)
{
  __shared__ u16 Kh[64][72], Kl[64][72];   // K tile [t][d],   144B rows
  __shared__ u16 Vh[64][72], Vl[64][72];   // V^T tile [d][t]
  __shared__ u16 Ph[64][72], Pl[64][72];   // P tile  [q][t], wave-local rows
  const int tid = threadIdx.x;
  const int lane = tid & 63, w = tid >> 6;
  const int lg = lane >> 4, lt = lane & 15;
  const int h = blockIdx.y, s0 = blockIdx.x * 64;
  const int qrow = s0 + w * 16 + lt;       // this lane's q row (B-frag / mask / store)

  // Q B-fragments, loaded once
  const size_t qbase = ((size_t)h * S + qrow) * 64;
  bf16x8 Qh_[2], Ql_[2];
  Qh_[0] = *(const bf16x8*)&qh[qbase + lg * 8];
  Qh_[1] = *(const bf16x8*)&qh[qbase + 32 + lg * 8];
  Ql_[0] = *(const bf16x8*)&ql[qbase + lg * 8];
  Ql_[1] = *(const bf16x8*)&ql[qbase + 32 + lg * 8];

  const size_t kbase = (size_t)h * S * 64;
  const size_t vbase = (size_t)h * 64 * S;

  f32x4 ao[4] = {};   // PV acc, fd = 0..3

  for (int t0 = 0; t0 < S; t0 += 64) {
    __syncthreads();   // previous tile's K/V reads complete
#pragma unroll
    for (int p = 0; p < 2; p++) {
      const int chunk = p * 256 + tid;          // 0..511
      const int row = chunk >> 3, c8 = (chunk & 7) * 8;
      *(uint4*)&Kh[row][c8] = *(const uint4*)&kh[kbase + (size_t)(t0 + row) * 64 + c8];
      *(uint4*)&Kl[row][c8] = *(const uint4*)&kl[kbase + (size_t)(t0 + row) * 64 + c8];
      *(uint4*)&Vh[row][c8] = *(const uint4*)&vTh[vbase + (size_t)row * S + t0 + c8];
      *(uint4*)&Vl[row][c8] = *(const uint4*)&vTl[vbase + (size_t)row * S + t0 + c8];
    }
    __syncthreads();

    // S^T = K·Q^T : D[t-block ft][q], t = ft*16 + lg*4 + r, q = lt
    f32x4 sct[4] = {};
#pragma unroll
    for (int ks = 0; ks < 2; ks++) {
#pragma unroll
      for (int ft = 0; ft < 4; ft++) {
        const bf16x8 ah = *(const bf16x8*)&Kh[ft * 16 + lt][ks * 32 + lg * 8];
        const bf16x8 al = *(const bf16x8*)&Kl[ft * 16 + lt][ks * 32 + lg * 8];
        sct[ft] = mfma3(ah, al, Qh_[ks], Ql_[ks], sct[ft]);
      }
    }

    // mask (int4) + raw-score store (float4) + P split (b64 LDS writes)
    const int* mrow = &mask[(size_t)qrow * S + t0];
    float* arow = &attn[((size_t)h * S + qrow) * S + t0];
#pragma unroll
    for (int ft = 0; ft < 4; ft++) {
      const int tl = ft * 16 + lg * 4;
      const int4 mv = *(const int4*)&mrow[tl];
      f32x4 sv = sct[ft];
      sv[0] = mv.x ? -1e-7f : sv[0];   // faithful reference quirk
      sv[1] = mv.y ? -1e-7f : sv[1];
      sv[2] = mv.z ? -1e-7f : sv[2];
      sv[3] = mv.w ? -1e-7f : sv[3];
      *(float4*)&arow[tl] = make_float4(sv[0], sv[1], sv[2], sv[3]);
      u16x4 h4, l4;
      split2v(sv[0], h4, l4, 0); split2v(sv[1], h4, l4, 1);
      split2v(sv[2], h4, l4, 2); split2v(sv[3], h4, l4, 3);
      *(u16x4*)&Ph[w * 16 + lt][tl] = h4;
      *(u16x4*)&Pl[w * 16 + lt][tl] = l4;
    }

    // PV: out[q][d] += P[q][t]·V^T[d][t]. P rows are wave-local; same-wave
    // LDS ops execute in order, so no barrier between P write and read.
#pragma unroll
    for (int ks = 0; ks < 2; ks++) {
      const bf16x8 pa_h = *(const bf16x8*)&Ph[w * 16 + lt][ks * 32 + lg * 8];
      const bf16x8 pa_l = *(const bf16x8*)&Pl[w * 16 + lt][ks * 32 + lg * 8];
#pragma unroll
      for (int fd = 0; fd < 4; fd++) {
        const bf16x8 vb_h = *(const bf16x8*)&Vh[fd * 16 + lt][ks * 32 + lg * 8];
        const bf16x8 vb_l = *(const bf16x8*)&Vl[fd * 16 + lt][ks * 32 + lg * 8];
        ao[fd] = mfma3(pa_h, pa_l, vb_h, vb_l, ao[fd]);
      }
    }
  }

  // concat write (split hi/lo): q = s0 + w*16 + lg*4 + r, d = h*64 + fd*16 + lt
#pragma unroll
  for (int fd = 0; fd < 4; fd++)
#pragma unroll
    for (int r = 0; r < 4; r++) {
      const int qg = s0 + w * 16 + lg * 4 + r;
      const int d = h * 64 + fd * 16 + lt;
      u16 hh, ll;
      split2(ao[fd][r], hh, ll);
      ch[(size_t)qg * DM + d] = hh;
      cl[(size_t)qg * DM + d] = ll;
    }
}

// ------------- row softmax on stored raw scores (read+write once) -----------
__global__ __launch_bounds__(256)
void softmax_fix(float* __restrict__ attn)
{
  float* row = attn + (size_t)blockIdx.x * S;
  const int tid = threadIdx.x;
  float4 a = ((const float4*)row)[tid];
  float4 b = ((const float4*)row)[tid + 256];

  float m = fmaxf(fmaxf(fmaxf(a.x, a.y), fmaxf(a.z, a.w)),
                  fmaxf(fmaxf(b.x, b.y), fmaxf(b.z, b.w)));
#pragma unroll
  for (int off = 32; off >= 1; off >>= 1)
    m = fmaxf(m, __shfl_xor(m, off));
  __shared__ float redm[4], reds[4];
  if ((tid & 63) == 0) redm[tid >> 6] = m;
  __syncthreads();
  m = fmaxf(fmaxf(redm[0], redm[1]), fmaxf(redm[2], redm[3]));

  a.x = __expf(a.x - m); a.y = __expf(a.y - m);
  a.z = __expf(a.z - m); a.w = __expf(a.w - m);
  b.x = __expf(b.x - m); b.y = __expf(b.y - m);
  b.z = __expf(b.z - m); b.w = __expf(b.w - m);
  float s = a.x + a.y + a.z + a.w + b.x + b.y + b.z + b.w;
#pragma unroll
  for (int off = 32; off >= 1; off >>= 1)
    s += __shfl_xor(s, off);
  if ((tid & 63) == 0) reds[tid >> 6] = s;
  __syncthreads();
  s = reds[0] + reds[1] + reds[2] + reds[3];

  const float inv = 1.0f / s;
  a.x *= inv; a.y *= inv; a.z *= inv; a.w *= inv;
  b.x *= inv; b.y *= inv; b.z *= inv; b.w *= inv;
  ((float4*)row)[tid] = a;
  ((float4*)row)[tid + 256] = b;
}

// ---------------- output projection: A pre-split concat, B = Wo fp32 --------
__global__ __launch_bounds__(256)
void out_proj(const u16* __restrict__ ch, const u16* __restrict__ cl,
              const float* __restrict__ Wo, float* __restrict__ out)
{
  __shared__ u16 Ah[128][40], Al[128][40], Bh[128][40], Bl[128][40];
  const int tid = threadIdx.x;
  const int lane = tid & 63, w = tid >> 6;
  const int wr = w >> 1, wc = w & 1;
  const int lg = lane >> 4, lt = lane & 15;
  const int m0 = blockIdx.x * 128, n0 = blockIdx.y * 128;

  f32x4 acc[4][4] = {};

  for (int k0 = 0; k0 < DM; k0 += 32) {
    uint4 ahv[2], alv[2];
    float4 bv[4];
#pragma unroll
    for (int p = 0; p < 2; p++) {
      const int chunk = p * 256 + tid;
      const int row = chunk >> 2, c8 = (chunk & 3) * 8;
      ahv[p] = *(const uint4*)&ch[(size_t)(m0 + row) * DM + k0 + c8];
      alv[p] = *(const uint4*)&cl[(size_t)(m0 + row) * DM + k0 + c8];
    }
#pragma unroll
    for (int p = 0; p < 4; p++) {
      const int idx = p * 256 + tid;
      const int row = idx >> 3, c4 = (idx & 7) * 4;
      bv[p] = *(const float4*)&Wo[(size_t)(n0 + row) * DM + k0 + c4];
    }
    __syncthreads();
#pragma unroll
    for (int p = 0; p < 2; p++) {
      const int chunk = p * 256 + tid;
      const int row = chunk >> 2, c8 = (chunk & 3) * 8;
      *(uint4*)&Ah[row][c8] = ahv[p];
      *(uint4*)&Al[row][c8] = alv[p];
    }
#pragma unroll
    for (int p = 0; p < 4; p++) {
      const int idx = p * 256 + tid;
      const int row = idx >> 3, c4 = (idx & 7) * 4;
      u16x4 h4, l4;
      split2v(bv[p].x, h4, l4, 0); split2v(bv[p].y, h4, l4, 1);
      split2v(bv[p].z, h4, l4, 2); split2v(bv[p].w, h4, l4, 3);
      *(u16x4*)&Bh[row][c4] = h4; *(u16x4*)&Bl[row][c4] = l4;
    }
    __syncthreads();

    bf16x8 bhf[4], blf[4];
#pragma unroll
    for (int fj = 0; fj < 4; fj++) {
      const int r = wc * 64 + fj * 16 + lt;
      bhf[fj] = *(const bf16x8*)&Bh[r][lg * 8];
      blf[fj] = *(const bf16x8*)&Bl[r][lg * 8];
    }
#pragma unroll
    for (int fi = 0; fi < 4; fi++) {
      const int r = wr * 64 + fi * 16 + lt;
      const bf16x8 ahf = *(const bf16x8*)&Ah[r][lg * 8];
      const bf16x8 alf = *(const bf16x8*)&Al[r][lg * 8];
#pragma unroll
      for (int fj = 0; fj < 4; fj++)
        acc[fi][fj] = mfma3(ahf, alf, bhf[fj], blf[fj], acc[fi][fj]);
    }
  }

#pragma unroll
  for (int fi = 0; fi < 4; fi++)
#pragma unroll
    for (int r = 0; r < 4; r++) {
      const int m = m0 + wr * 64 + fi * 16 + lg * 4 + r;
#pragma unroll
      for (int fj = 0; fj < 4; fj++) {
        const int n = n0 + wc * 64 + fj * 16 + lt;
        out[(size_t)m * DM + n] = acc[fi][fj][r];
      }
    }
}

// ---------------------------------------------------------------------------
extern "C" void kernel_launch(void* const* d_in, const int* in_sizes, int n_in,
                              void* d_out, int out_size, void* d_ws, size_t ws_size,
                              hipStream_t stream)
{
  const float* query = (const float*)d_in[0];
  const float* key   = (const float*)d_in[1];
  const float* value = (const float*)d_in[2];
  const int*   mask  = (const int*)d_in[3];
  const float* Wq    = (const float*)d_in[4];
  const float* Wk    = (const float*)d_in[5];
  const float* Wv    = (const float*)d_in[6];
  const float* Wo    = (const float*)d_in[7];

  float* out  = (float*)d_out;                 // [S][DM]
  float* attn = out + (size_t)S * DM;          // [H][S][S]

  const size_t NE = (size_t)H * S * 64;        // 2,097,152
  u16* qh  = (u16*)d_ws;                       // 8 arrays x 4 MB = 32 MB
  u16* ql  = qh  + NE;
  u16* kh  = ql  + NE;
  u16* kl  = kh  + NE;
  u16* vTh = kl  + NE;                         // [DM][S]
  u16* vTl = vTh + NE;
  u16* ch  = vTl + NE;                         // [S][DM]
  u16* cl  = ch  + NE;

  hipLaunchKernelGGL(qkv_proj, dim3(16, 8, 3), dim3(256), 0, stream,
                     query, key, value, Wq, Wk, Wv, qh, ql, kh, kl, vTh, vTl);

  hipLaunchKernelGGL(attn_pv, dim3(S / 64, H), dim3(256), 0, stream,
                     qh, ql, kh, kl, vTh, vTl, mask, attn, ch, cl);

  hipLaunchKernelGGL(softmax_fix, dim3(H * S), dim3(256), 0, stream, attn);

  hipLaunchKernelGGL(out_proj, dim3(16, 8), dim3(256), 0, stream,
                     ch, cl, Wo, out);
}

// Round 7
// 579.592 us; speedup vs baseline: 1.5932x; 1.0611x over previous
//
#include <hip/hip_runtime.h>

#define S 2048
#define DM 1024
#define H 16
#define DH 64

typedef __attribute__((ext_vector_type(8))) short bf16x8;
typedef __attribute__((ext_vector_type(4))) float f32x4;
typedef __attribute__((ext_vector_type(4))) unsigned short u16x4;
typedef unsigned short u16;
typedef unsigned int u32;

// trunc-split: x = hi + rem; hi = upper-16(x) (exact), lo = RNE-bf16(rem).
// |x - hi - lo| <~ 2^-16 |x|
__device__ __forceinline__ void split2(float x, u16& h, u16& l) {
  const u32 u = __float_as_uint(x);
  const u32 hu = u & 0xFFFF0000u;
  h = (u16)(hu >> 16);
  const float rem = x - __uint_as_float(hu);
  u32 r = __float_as_uint(rem);
  r += 0x7FFFu + ((r >> 16) & 1u);
  l = (u16)(r >> 16);
}

// split into vector slots via plain temporaries (vector elements can't bind
// to non-const refs). Call with compile-time i inside unrolled loops.
__device__ __forceinline__ void split2v(float x, u16x4& h4, u16x4& l4, int i) {
  u16 hh, ll;
  split2(x, hh, ll);
  h4[i] = hh; l4[i] = ll;
}

// c += (ah+al)*(bh+bl) dropping al*bl
__device__ __forceinline__ f32x4 mfma3(bf16x8 ah, bf16x8 al, bf16x8 bh, bf16x8 bl, f32x4 c) {
  c = __builtin_amdgcn_mfma_f32_16x16x32_bf16(ah, bh, c, 0, 0, 0);
  c = __builtin_amdgcn_mfma_f32_16x16x32_bf16(ah, bl, c, 0, 0, 0);
  c = __builtin_amdgcn_mfma_f32_16x16x32_bf16(al, bh, c, 0, 0, 0);
  return c;
}

// ---------------- QKV projection: NT GEMM, split bf16 hi/lo output ----------
// z=0: Q = X_q·Wq^T, head-major [H][S][64], pre-scaled 0.125
// z=1: K = X_k·Wk^T, head-major
// z=2: V^T = Wv·X_v^T, row-major [DM][S]  (A=Wv rows d, B=X rows s)
__global__ __launch_bounds__(256)
void qkv_proj(const float* __restrict__ q, const float* __restrict__ k,
              const float* __restrict__ v, const float* __restrict__ Wq,
              const float* __restrict__ Wk, const float* __restrict__ Wv,
              u16* __restrict__ qh, u16* __restrict__ ql,
              u16* __restrict__ kh, u16* __restrict__ kl,
              u16* __restrict__ vTh, u16* __restrict__ vTl)
{
  __shared__ u16 Ah[128][40], Al[128][40], Bh[128][40], Bl[128][40]; // 80B rows
  const int tid = threadIdx.x;
  const int lane = tid & 63, w = tid >> 6;
  const int wr = w >> 1, wc = w & 1;
  const int lg = lane >> 4, lt = lane & 15;
  const int z = blockIdx.z;

  const float *A, *B;
  int m0, n0;
  if (z == 2) { A = Wv; B = v; m0 = blockIdx.y * 128; n0 = blockIdx.x * 128; }
  else {
    A = (z == 0) ? q : k; B = (z == 0) ? Wq : Wk;
    m0 = blockIdx.x * 128; n0 = blockIdx.y * 128;
  }

  f32x4 acc[4][4] = {};

  for (int k0 = 0; k0 < DM; k0 += 32) {
    float4 av[4], bv[4];
#pragma unroll
    for (int p = 0; p < 4; p++) {
      const int idx = p * 256 + tid;
      const int row = idx >> 3, c4 = (idx & 7) * 4;
      av[p] = *(const float4*)&A[(size_t)(m0 + row) * DM + k0 + c4];
      bv[p] = *(const float4*)&B[(size_t)(n0 + row) * DM + k0 + c4];
    }
    __syncthreads();                      // prev iter done reading LDS
#pragma unroll
    for (int p = 0; p < 4; p++) {
      const int idx = p * 256 + tid;
      const int row = idx >> 3, c4 = (idx & 7) * 4;
      u16x4 h4, l4;
      split2v(av[p].x, h4, l4, 0); split2v(av[p].y, h4, l4, 1);
      split2v(av[p].z, h4, l4, 2); split2v(av[p].w, h4, l4, 3);
      *(u16x4*)&Ah[row][c4] = h4; *(u16x4*)&Al[row][c4] = l4;
      split2v(bv[p].x, h4, l4, 0); split2v(bv[p].y, h4, l4, 1);
      split2v(bv[p].z, h4, l4, 2); split2v(bv[p].w, h4, l4, 3);
      *(u16x4*)&Bh[row][c4] = h4; *(u16x4*)&Bl[row][c4] = l4;
    }
    __syncthreads();

    bf16x8 bhf[4], blf[4];
#pragma unroll
    for (int fj = 0; fj < 4; fj++) {
      const int r = wc * 64 + fj * 16 + lt;
      bhf[fj] = *(const bf16x8*)&Bh[r][lg * 8];
      blf[fj] = *(const bf16x8*)&Bl[r][lg * 8];
    }
#pragma unroll
    for (int fi = 0; fi < 4; fi++) {
      const int r = wr * 64 + fi * 16 + lt;
      const bf16x8 ahf = *(const bf16x8*)&Ah[r][lg * 8];
      const bf16x8 alf = *(const bf16x8*)&Al[r][lg * 8];
#pragma unroll
      for (int fj = 0; fj < 4; fj++)
        acc[fi][fj] = mfma3(ahf, alf, bhf[fj], blf[fj], acc[fi][fj]);
    }
  }

  u16 *dh, *dl;
  float scale;
  if (z == 0)      { dh = qh;  dl = ql;  scale = 0.125f; }
  else if (z == 1) { dh = kh;  dl = kl;  scale = 1.0f; }
  else             { dh = vTh; dl = vTl; scale = 1.0f; }

#pragma unroll
  for (int fi = 0; fi < 4; fi++)
#pragma unroll
    for (int r = 0; r < 4; r++) {
      const int m = m0 + wr * 64 + fi * 16 + lg * 4 + r;
#pragma unroll
      for (int fj = 0; fj < 4; fj++) {
        const int n = n0 + wc * 64 + fj * 16 + lt;
        const size_t addr = (z == 2) ? ((size_t)m * S + n)
                                     : ((size_t)((n >> 6) * S + m) * 64 + (n & 63));
        u16 hh, ll;
        split2(acc[fi][fj][r] * scale, hh, ll);
        dh[addr] = hh; dl[addr] = ll;
      }
    }
}

// -------- fused attention: PV on raw masked scores + online (m,l) stats
// -------- (phase 1), QK^T recompute + direct normalized softmax (phase 2).
// block = (64 q-rows, head); 4 waves, each owns 16 q-rows, full t extent.
// Scores computed TRANSPOSED (mfma(K,Q)): lane holds 4 consecutive t per reg;
// all of a q-row's tile values live in the 4 lanes sharing lt -> stats via
// __shfl_xor(16|32).
__global__ __launch_bounds__(256)
void attn_pv(const u16* __restrict__ qh, const u16* __restrict__ ql,
             const u16* __restrict__ kh, const u16* __restrict__ kl,
             const u16* __restrict__ vTh, const u16* __restrict__ vTl,
             const int* __restrict__ mask,
             float* __restrict__ attn, u16* __restrict__ ch, u16* __restrict__ cl)
{
  __shared__ u16 Kh[64][72], Kl[64][72];   // K tile [t][d],   144B rows
  __shared__ u16 Vh[64][72], Vl[64][72];   // V^T tile [d][t]
  __shared__ u16 Ph[64][72], Pl[64][72];   // P tile  [q][t], wave-local rows
  const int tid = threadIdx.x;
  const int lane = tid & 63, w = tid >> 6;
  const int lg = lane >> 4, lt = lane & 15;
  const int h = blockIdx.y, s0 = blockIdx.x * 64;
  const int qrow = s0 + w * 16 + lt;       // this lane's q row (B-frag / mask / store)

  // Q B-fragments, loaded once
  const size_t qbase = ((size_t)h * S + qrow) * 64;
  bf16x8 Qh_[2], Ql_[2];
  Qh_[0] = *(const bf16x8*)&qh[qbase + lg * 8];
  Qh_[1] = *(const bf16x8*)&qh[qbase + 32 + lg * 8];
  Ql_[0] = *(const bf16x8*)&ql[qbase + lg * 8];
  Ql_[1] = *(const bf16x8*)&ql[qbase + 32 + lg * 8];

  const size_t kbase = (size_t)h * S * 64;
  const size_t vbase = (size_t)h * 64 * S;

  f32x4 ao[4] = {};                 // PV acc, fd = 0..3
  float m_run = -3.0e38f, l_run = 0.0f;   // softmax stats for q = lt's row

  // =============================== phase 1 ================================
  for (int t0 = 0; t0 < S; t0 += 64) {
    __syncthreads();   // previous tile's K/V reads complete
#pragma unroll
    for (int p = 0; p < 2; p++) {
      const int chunk = p * 256 + tid;          // 0..511
      const int row = chunk >> 3, c8 = (chunk & 7) * 8;
      *(uint4*)&Kh[row][c8] = *(const uint4*)&kh[kbase + (size_t)(t0 + row) * 64 + c8];
      *(uint4*)&Kl[row][c8] = *(const uint4*)&kl[kbase + (size_t)(t0 + row) * 64 + c8];
      *(uint4*)&Vh[row][c8] = *(const uint4*)&vTh[vbase + (size_t)row * S + t0 + c8];
      *(uint4*)&Vl[row][c8] = *(const uint4*)&vTl[vbase + (size_t)row * S + t0 + c8];
    }
    __syncthreads();

    // S^T = K·Q^T : D[t-block ft][q], t = ft*16 + lg*4 + r, q = lt
    f32x4 sct[4] = {};
#pragma unroll
    for (int ks = 0; ks < 2; ks++) {
#pragma unroll
      for (int ft = 0; ft < 4; ft++) {
        const bf16x8 ah = *(const bf16x8*)&Kh[ft * 16 + lt][ks * 32 + lg * 8];
        const bf16x8 al = *(const bf16x8*)&Kl[ft * 16 + lt][ks * 32 + lg * 8];
        sct[ft] = mfma3(ah, al, Qh_[ks], Ql_[ks], sct[ft]);
      }
    }

    // mask (int4) + P split (b64 LDS writes) + per-lane partial max
    const int* mrow = &mask[(size_t)qrow * S + t0];
    float pm = -3.0e38f;
#pragma unroll
    for (int ft = 0; ft < 4; ft++) {
      const int tl = ft * 16 + lg * 4;
      const int4 mv = *(const int4*)&mrow[tl];
      f32x4 sv = sct[ft];
      sv[0] = mv.x ? -1e-7f : sv[0];   // faithful reference quirk
      sv[1] = mv.y ? -1e-7f : sv[1];
      sv[2] = mv.z ? -1e-7f : sv[2];
      sv[3] = mv.w ? -1e-7f : sv[3];
      sct[ft] = sv;                    // keep masked values for stats
      pm = fmaxf(pm, fmaxf(fmaxf(sv[0], sv[1]), fmaxf(sv[2], sv[3])));
      u16x4 h4, l4;
      split2v(sv[0], h4, l4, 0); split2v(sv[1], h4, l4, 1);
      split2v(sv[2], h4, l4, 2); split2v(sv[3], h4, l4, 3);
      *(u16x4*)&Ph[w * 16 + lt][tl] = h4;
      *(u16x4*)&Pl[w * 16 + lt][tl] = l4;
    }

    // online (m,l) update: q-row's 64 tile values live in lanes sharing lt
    pm = fmaxf(pm, __shfl_xor(pm, 16));
    pm = fmaxf(pm, __shfl_xor(pm, 32));
    const float mn = fmaxf(m_run, pm);
    float es = 0.0f;
#pragma unroll
    for (int ft = 0; ft < 4; ft++) {
      es += __expf(sct[ft][0] - mn) + __expf(sct[ft][1] - mn)
          + __expf(sct[ft][2] - mn) + __expf(sct[ft][3] - mn);
    }
    es += __shfl_xor(es, 16);
    es += __shfl_xor(es, 32);
    l_run = l_run * __expf(m_run - mn) + es;
    m_run = mn;

    // PV: out[q][d] += P[q][t]·V^T[d][t]. P rows are wave-local; same-wave
    // LDS ops execute in order, so no barrier between P write and read.
#pragma unroll
    for (int ks = 0; ks < 2; ks++) {
      const bf16x8 pa_h = *(const bf16x8*)&Ph[w * 16 + lt][ks * 32 + lg * 8];
      const bf16x8 pa_l = *(const bf16x8*)&Pl[w * 16 + lt][ks * 32 + lg * 8];
#pragma unroll
      for (int fd = 0; fd < 4; fd++) {
        const bf16x8 vb_h = *(const bf16x8*)&Vh[fd * 16 + lt][ks * 32 + lg * 8];
        const bf16x8 vb_l = *(const bf16x8*)&Vl[fd * 16 + lt][ks * 32 + lg * 8];
        ao[fd] = mfma3(pa_h, pa_l, vb_h, vb_l, ao[fd]);
      }
    }
  }

  // concat write (split hi/lo): q = s0 + w*16 + lg*4 + r, d = h*64 + fd*16 + lt
  // (done before phase 2 so the ao accumulators die here)
#pragma unroll
  for (int fd = 0; fd < 4; fd++)
#pragma unroll
    for (int r = 0; r < 4; r++) {
      const int qg = s0 + w * 16 + lg * 4 + r;
      const int d = h * 64 + fd * 16 + lt;
      u16 hh, ll;
      split2(ao[fd][r], hh, ll);
      ch[(size_t)qg * DM + d] = hh;
      cl[(size_t)qg * DM + d] = ll;
    }

  // ========= phase 2: recompute QK^T, write normalized softmax once ========
  const float fm  = m_run;
  const float fil = 1.0f / l_run;

  for (int t0 = 0; t0 < S; t0 += 64) {
    __syncthreads();   // previous tile's K reads complete
#pragma unroll
    for (int p = 0; p < 2; p++) {
      const int chunk = p * 256 + tid;
      const int row = chunk >> 3, c8 = (chunk & 7) * 8;
      *(uint4*)&Kh[row][c8] = *(const uint4*)&kh[kbase + (size_t)(t0 + row) * 64 + c8];
      *(uint4*)&Kl[row][c8] = *(const uint4*)&kl[kbase + (size_t)(t0 + row) * 64 + c8];
    }
    __syncthreads();

    f32x4 sct[4] = {};
#pragma unroll
    for (int ks = 0; ks < 2; ks++) {
#pragma unroll
      for (int ft = 0; ft < 4; ft++) {
        const bf16x8 ah = *(const bf16x8*)&Kh[ft * 16 + lt][ks * 32 + lg * 8];
        const bf16x8 al = *(const bf16x8*)&Kl[ft * 16 + lt][ks * 32 + lg * 8];
        sct[ft] = mfma3(ah, al, Qh_[ks], Ql_[ks], sct[ft]);
      }
    }

    const int* mrow = &mask[(size_t)qrow * S + t0];
    float* arow = &attn[((size_t)h * S + qrow) * S + t0];
#pragma unroll
    for (int ft = 0; ft < 4; ft++) {
      const int tl = ft * 16 + lg * 4;
      const int4 mv = *(const int4*)&mrow[tl];
      f32x4 sv = sct[ft];
      sv[0] = mv.x ? -1e-7f : sv[0];
      sv[1] = mv.y ? -1e-7f : sv[1];
      sv[2] = mv.z ? -1e-7f : sv[2];
      sv[3] = mv.w ? -1e-7f : sv[3];
      const float4 o = make_float4(__expf(sv[0] - fm) * fil,
                                   __expf(sv[1] - fm) * fil,
                                   __expf(sv[2] - fm) * fil,
                                   __expf(sv[3] - fm) * fil);
      *(float4*)&arow[tl] = o;
    }
  }
}

// ---------------- output projection: A pre-split concat, B = Wo fp32 --------
__global__ __launch_bounds__(256)
void out_proj(const u16* __restrict__ ch, const u16* __restrict__ cl,
              const float* __restrict__ Wo, float* __restrict__ out)
{
  __shared__ u16 Ah[128][40], Al[128][40], Bh[128][40], Bl[128][40];
  const int tid = threadIdx.x;
  const int lane = tid & 63, w = tid >> 6;
  const int wr = w >> 1, wc = w & 1;
  const int lg = lane >> 4, lt = lane & 15;
  const int m0 = blockIdx.x * 128, n0 = blockIdx.y * 128;

  f32x4 acc[4][4] = {};

  for (int k0 = 0; k0 < DM; k0 += 32) {
    uint4 ahv[2], alv[2];
    float4 bv[4];
#pragma unroll
    for (int p = 0; p < 2; p++) {
      const int chunk = p * 256 + tid;
      const int row = chunk >> 2, c8 = (chunk & 3) * 8;
      ahv[p] = *(const uint4*)&ch[(size_t)(m0 + row) * DM + k0 + c8];
      alv[p] = *(const uint4*)&cl[(size_t)(m0 + row) * DM + k0 + c8];
    }
#pragma unroll
    for (int p = 0; p < 4; p++) {
      const int idx = p * 256 + tid;
      const int row = idx >> 3, c4 = (idx & 7) * 4;
      bv[p] = *(const float4*)&Wo[(size_t)(n0 + row) * DM + k0 + c4];
    }
    __syncthreads();
#pragma unroll
    for (int p = 0; p < 2; p++) {
      const int chunk = p * 256 + tid;
      const int row = chunk >> 2, c8 = (chunk & 3) * 8;
      *(uint4*)&Ah[row][c8] = ahv[p];
      *(uint4*)&Al[row][c8] = alv[p];
    }
#pragma unroll
    for (int p = 0; p < 4; p++) {
      const int idx = p * 256 + tid;
      const int row = idx >> 3, c4 = (idx & 7) * 4;
      u16x4 h4, l4;
      split2v(bv[p].x, h4, l4, 0); split2v(bv[p].y, h4, l4, 1);
      split2v(bv[p].z, h4, l4, 2); split2v(bv[p].w, h4, l4, 3);
      *(u16x4*)&Bh[row][c4] = h4; *(u16x4*)&Bl[row][c4] = l4;
    }
    __syncthreads();

    bf16x8 bhf[4], blf[4];
#pragma unroll
    for (int fj = 0; fj < 4; fj++) {
      const int r = wc * 64 + fj * 16 + lt;
      bhf[fj] = *(const bf16x8*)&Bh[r][lg * 8];
      blf[fj] = *(const bf16x8*)&Bl[r][lg * 8];
    }
#pragma unroll
    for (int fi = 0; fi < 4; fi++) {
      const int r = wr * 64 + fi * 16 + lt;
      const bf16x8 ahf = *(const bf16x8*)&Ah[r][lg * 8];
      const bf16x8 alf = *(const bf16x8*)&Al[r][lg * 8];
#pragma unroll
      for (int fj = 0; fj < 4; fj++)
        acc[fi][fj] = mfma3(ahf, alf, bhf[fj], blf[fj], acc[fi][fj]);
    }
  }

#pragma unroll
  for (int fi = 0; fi < 4; fi++)
#pragma unroll
    for (int r = 0; r < 4; r++) {
      const int m = m0 + wr * 64 + fi * 16 + lg * 4 + r;
#pragma unroll
      for (int fj = 0; fj < 4; fj++) {
        const int n = n0 + wc * 64 + fj * 16 + lt;
        out[(size_t)m * DM + n] = acc[fi][fj][r];
      }
    }
}

// ---------------------------------------------------------------------------
extern "C" void kernel_launch(void* const* d_in, const int* in_sizes, int n_in,
                              void* d_out, int out_size, void* d_ws, size_t ws_size,
                              hipStream_t stream)
{
  const float* query = (const float*)d_in[0];
  const float* key   = (const float*)d_in[1];
  const float* value = (const float*)d_in[2];
  const int*   mask  = (const int*)d_in[3];
  const float* Wq    = (const float*)d_in[4];
  const float* Wk    = (const float*)d_in[5];
  const float* Wv    = (const float*)d_in[6];
  const float* Wo    = (const float*)d_in[7];

  float* out  = (float*)d_out;                 // [S][DM]
  float* attn = out + (size_t)S * DM;          // [H][S][S]

  const size_t NE = (size_t)H * S * 64;        // 2,097,152
  u16* qh  = (u16*)d_ws;                       // 8 arrays x 4 MB = 32 MB
  u16* ql  = qh  + NE;
  u16* kh  = ql  + NE;
  u16* kl  = kh  + NE;
  u16* vTh = kl  + NE;                         // [DM][S]
  u16* vTl = vTh + NE;
  u16* ch  = vTl + NE;                         // [S][DM]
  u16* cl  = ch  + NE;

  hipLaunchKernelGGL(qkv_proj, dim3(16, 8, 3), dim3(256), 0, stream,
                     query, key, value, Wq, Wk, Wv, qh, ql, kh, kl, vTh, vTl);

  hipLaunchKernelGGL(attn_pv, dim3(S / 64, H), dim3(256), 0, stream,
                     qh, ql, kh, kl, vTh, vTl, mask, attn, ch, cl);

  hipLaunchKernelGGL(out_proj, dim3(16, 8), dim3(256), 0, stream,
                     ch, cl, Wo, out);
}